// Round 16
// baseline (317.554 us; speedup 1.0000x reference)
//
#include <hip/hip_runtime.h>
#include <hip/hip_bf16.h>
#include <math.h>

typedef __hip_bfloat16 bf16;
typedef short short8 __attribute__((ext_vector_type(8)));
typedef float floatx4 __attribute__((ext_vector_type(4)));

#define NB 16
#define NC 256
#define NHW 1024
#define NNE 256
#define NP (NB*NC*NHW)

__device__ __forceinline__ unsigned short f2bu(float f){
  bf16 h = (bf16)f; return *(unsigned short*)&h;
}

// async 16B global -> LDS DMA (no VGPR round-trip; per-lane global src, linear LDS dest)
__device__ __forceinline__ void gload_lds16(const short* g, short* l){
  __builtin_amdgcn_global_load_lds(
      (const __attribute__((address_space(1))) void*)g,
      (__attribute__((address_space(3))) void*)l, 16, 0, 0);
}

// ---------------- MEGA-PREP: wprep3 + wprep1 + cvtc + noise + gn_t in ONE launch ------------
__global__ __launch_bounds__(256)
void prep_mega_kernel(const float* __restrict__ w1, const float* __restrict__ w2,
                      short* __restrict__ wp1, short* __restrict__ wp2,
                      float* __restrict__ st,
                      const float* __restrict__ wq, const float* __restrict__ wc,
                      const float* __restrict__ wo,
                      short* __restrict__ wqp, short* __restrict__ wcp,
                      short* __restrict__ wop,
                      const float* __restrict__ c_in, short* __restrict__ cp,
                      const float* __restrict__ emb, const float* __restrict__ nw,
                      const float* __restrict__ nb, float* __restrict__ na,
                      const float* __restrict__ x, const float* __restrict__ gn1_g,
                      const float* __restrict__ gn1_b, short* __restrict__ xp){
  __shared__ float smem[8224];            // 32.9 KB arena (cvtc needs 32*257)
  const int blk = blockIdx.x, tid = threadIdx.x;

  if (blk < 512){                         // ---- wprep3 ----
    int co = blk & 255;
    const float* w = (blk < 256) ? w1 : w2;
    short* wp = (blk < 256) ? wp1 : wp2;
    if (blk == 0){
      for (int i=tid;i<4096;i+=256) st[i] = 0.f;   // stats (2048) + zpad (2048 floats)
    }
    float* tmp = smem;                    // 2304 floats
    for (int i=tid;i<2304;i+=256) tmp[i] = w[(size_t)co*2304 + i];
    __syncthreads();
    for (int j=tid;j<2304;j+=256){
      int tap = j>>8, ci = j&255;
      wp[(((size_t)tap*8 + (ci>>5))*NC + co)*32 + (ci&31)] = (short)f2bu(tmp[ci*9 + tap]);
    }
  } else if (blk < 1792){                 // ---- wprep1 ----
    int bq = blk - 512;
    if (bq < 768){
      float v = wq[(size_t)bq*256 + tid];
      wqp[(((size_t)(tid>>5))*768 + bq)*32 + (tid&31)] = (short)f2bu(v);
    } else if (bq < 1024){
      int co = bq - 768;
      float v = wc[(size_t)co*256 + tid];
      wcp[(((size_t)(tid>>5))*256 + co)*32 + (tid&31)] = (short)f2bu(v);
    } else {
      int co = bq - 1024;
      float v = wo[(size_t)co*256 + tid];
      wop[(((size_t)(tid>>5))*256 + co)*32 + (tid&31)] = (short)f2bu(v);
    }
  } else if (blk < 2304){                 // ---- cvtc ----
    int j = blk - 1792;
    int pxc = j&3, cc = (j>>2)&7, b = j>>5;
    float* ld = smem;                     // [32][257]
    size_t gbase = ((size_t)b*NC + cc*32)*NHW + pxc*256;
    for (int r=0;r<32;r++) ld[r*257 + tid] = c_in[gbase + (size_t)r*NHW + tid];
    __syncthreads();
    short* dst = cp + (((size_t)b*8 + cc)*NHW + pxc*256)*32;
    for (int it=0;it<4;it++){
      int pxl = it*64 + (tid>>2), ckl = tid&3;
      short8 pk;
      #pragma unroll
      for (int e=0;e<8;e++) pk[e] = (short)f2bu(ld[(ckl*8+e)*257 + pxl]);
      *(short8*)(dst + (size_t)pxl*32 + ckl*8) = pk;
    }
  } else if (blk < 2320){                 // ---- noise ----
    int b = blk - 2304, c = tid;
    float* e = smem;
    e[c] = emb[b*NNE + c];
    __syncthreads();
    float acc = nb[c];
    for (int k=0;k<NNE;k++) acc += e[k]*nw[c*NNE+k];
    na[b*NC + c] = acc;
  } else {                                // ---- gn_t (gn1 + swish -> xp) ----
    int j = blk - 2320;
    int b = j >> 5, g = j & 31;
    const int GSZ = 8*NHW;
    size_t base = ((size_t)b*NC + g*8)*NHW;
    float s = 0.f, ss = 0.f;
    for (int i = tid; i < GSZ; i += 256){
      float v = x[base+i];
      s += v; ss += v*v;
    }
    float* rs = smem; float* rq = smem + 256;
    rs[tid] = s; rq[tid] = ss;
    __syncthreads();
    for (int off=128; off>0; off>>=1){
      if (tid < off){ rs[tid]+=rs[tid+off]; rq[tid]+=rq[tid+off]; }
      __syncthreads();
    }
    float mean = rs[0] * (1.f/GSZ);
    float var  = rq[0] * (1.f/GSZ) - mean*mean;
    float inv  = rsqrtf(var + 1e-5f);
    float gm[8], bt[8];
    #pragma unroll
    for (int jj=0;jj<8;jj++){ gm[jj] = gn1_g[g*8+jj]*inv; bt[jj] = gn1_b[g*8+jj]; }
    short* dst = xp + (((size_t)b*8 + (g>>2))*NHW)*32 + (g&3)*8;
    for (int px = tid; px < NHW; px += 256){
      short8 pk;
      #pragma unroll
      for (int jj=0;jj<8;jj++){
        float v = (x[base + jj*NHW + px] - mean)*gm[jj] + bt[jj];
        v = v / (1.f + __expf(-v));
        pk[jj] = (short)f2bu(v);
      }
      *(short8*)(dst + (size_t)px*32) = pk;
    }
  }
}

// ---------------- GroupNorm single-pass from precomputed stats ----------------
template<bool SWISH>
__global__ void gn_post_kernel(const float* __restrict__ src, const float* __restrict__ st,
                               const float* __restrict__ gamma, const float* __restrict__ beta,
                               short* __restrict__ xp){
  int b = blockIdx.x >> 5, g = blockIdx.x & 31;
  size_t base = ((size_t)b*NC + g*8)*NHW;
  int tid = threadIdx.x;
  float s  = st[(b*32+g)*2+0];
  float ss = st[(b*32+g)*2+1];
  float mean = s * (1.f/8192.f);
  float var  = ss * (1.f/8192.f) - mean*mean;
  float inv  = rsqrtf(var + 1e-5f);
  float gm[8], bt[8];
  #pragma unroll
  for (int j=0;j<8;j++){ gm[j] = gamma[g*8+j]*inv; bt[j] = beta[g*8+j]; }
  short* dst = xp + (((size_t)b*8 + (g>>2))*NHW)*32 + (g&3)*8;
  for (int px = tid; px < NHW; px += 256){
    short8 pk;
    #pragma unroll
    for (int j=0;j<8;j++){
      float v = (src[base + j*NHW + px] - mean)*gm[j] + bt[j];
      if (SWISH) v = v / (1.f + __expf(-v));
      pk[j] = (short)f2bu(v);
    }
    *(short8*)(dst + (size_t)px*32) = pk;
  }
}

// ---------------- MFMA conv3x3 (+ optional fused 1x1 cfunc as steps 36..39) -----------------
// Depth-2 counted-vmcnt pipeline (was depth-3): 2 LDS buffers (49 KB) -> 3 blocks/CU via
// launch_bounds(256,3). Per step: vmcnt(6) retires exactly the stage issued 2 steps (~3.2K cyc)
// ago (never stalls steady-state); STAGE(j+2) refills. More independent barrier groups per CU
// interleave the per-step cadence holes. T2 swizzle unchanged (conflicts==0).
template<int NSTEP>
__global__ __launch_bounds__(256,3)
void conv3_mfma_kernel(const short* __restrict__ xp, const short* __restrict__ wp,
                       const float* __restrict__ bias, const float* __restrict__ bias_bc,
                       const float* __restrict__ addf, float* __restrict__ out,
                       float* __restrict__ st, const short* __restrict__ zpad,
                       const short* __restrict__ cp2, const short* __restrict__ wcp2,
                       const float* __restrict__ bias2){
  const int b = blockIdx.z, bx = blockIdx.x, by = blockIdx.y;
  const int tid = threadIdx.x, wave = tid>>6, lane = tid&63;
  const int quad = lane>>4, lm = lane&15;
  const int co0 = by*64;
  const int px0 = bx*128, yb = bx*4;

  __shared__ short Sb0[12288], Sb1[12288]; // each: [0,4096)=A 64x64, [4096,12288)=B 128x64

  const int rowt = tid>>3;
  const int g2   = (tid&7) ^ ((tid>>3)&7); // logical granule feeding this linear slot
  const int kq2  = g2 & 3;
  const int ccs2 = g2 >> 2;
  const size_t b8 = (size_t)b*8*NHW*32;

  auto STAGE = [&](int j, short* S){
    if constexpr (NSTEP > 36){
      if (j >= 36){                        // ---- cfunc 1x1 step: cc = j-36 ----
        const int cc = j - 36;
        const short* wsrc = wcp2 + (size_t)(cc*2 + ccs2)*8192 + (co0 + rowt)*32 + kq2*8;
        #pragma unroll
        for (int i=0;i<2;i++)
          gload_lds16(wsrc + i*(32*32), S + tid*8 + i*2048);
        const short* xstep = cp2 + b8 + (size_t)(cc*2 + ccs2)*(NHW*32);
        #pragma unroll
        for (int i=0;i<4;i++)
          gload_lds16(xstep + ((yb+i)*32 + rowt)*32 + kq2*8, S + 4096 + tid*8 + i*2048);
        return;
      }
    }
    const int tap = j>>2, ccp = j&3;
    const int dyp = (tap*11)>>5;           // 0,0,0,1,1,1,2,2,2
    const int dx  = tap - dyp*3 - 1;
    const int dy  = dyp - 1;
    const short* wsrc = wp + (size_t)(tap*8 + ccp*2 + ccs2)*8192 + (co0 + rowt)*32 + kq2*8;
    #pragma unroll
    for (int i=0;i<2;i++)
      gload_lds16(wsrc + i*(32*32), S + tid*8 + i*2048);
    const short* xstep = xp + b8 + (size_t)(ccp*2 + ccs2)*(NHW*32);
    const int xx = rowt + dx;
    const bool xok = (unsigned)xx < 32u;
    #pragma unroll
    for (int i=0;i<4;i++){
      const int y = yb + i + dy;
      const short* src = (xok && (unsigned)y < 32u)
                       ? (xstep + (y*32 + xx)*32 + kq2*8)
                       : (zpad + kq2*8);
      gload_lds16(src, S + 4096 + tid*8 + i*2048);
    }
  };

  floatx4 acc[4][2];
  #pragma unroll
  for (int mt=0;mt<4;mt++)
    #pragma unroll
    for (int nt=0;nt<2;nt++) acc[mt][nt] = (floatx4){0.f,0.f,0.f,0.f};

  const int sl = lm & 7;                   // read-side swizzle key
  auto STEP = [&](int j, short* S){
    // retire exactly the 6 DMAs of stage j (issued 2 steps ago); keep stage j+1's 6 in flight
    asm volatile("s_waitcnt vmcnt(6)" ::: "memory");
    __builtin_amdgcn_s_barrier();
    __builtin_amdgcn_sched_barrier(0);
    short8 Af[2][4], Bf[2][2];
    #pragma unroll
    for (int ka=0;ka<2;ka++){
      const int slot = ((ka*4 + quad) ^ sl) << 3;
      #pragma unroll
      for (int mt=0;mt<4;mt++)
        Af[ka][mt] = *(const short8*)(S + (mt*16+lm)*64 + slot);
      #pragma unroll
      for (int nt=0;nt<2;nt++)
        Bf[ka][nt] = *(const short8*)(S + 4096 + (wave*32 + nt*16 + lm)*64 + slot);
    }
    asm volatile("s_waitcnt lgkmcnt(0)" ::: "memory");
    __builtin_amdgcn_sched_barrier(0);     // rule #18
    __builtin_amdgcn_s_barrier();
    int jn = j + 2; if (jn > NSTEP-1) jn = NSTEP-1;
    STAGE(jn, S);
    __builtin_amdgcn_s_setprio(1);
    #pragma unroll
    for (int ka=0;ka<2;ka++)
      #pragma unroll
      for (int mt=0;mt<4;mt++)
        #pragma unroll
        for (int nt=0;nt<2;nt++)
          acc[mt][nt] = __builtin_amdgcn_mfma_f32_16x16x32_bf16(Af[ka][mt], Bf[ka][nt], acc[mt][nt], 0,0,0);
    __builtin_amdgcn_s_setprio(0);
  };

  STAGE(0, Sb0); STAGE(1, Sb1);            // 12 DMAs in flight per wave
  for (int jt=0; jt<36; jt+=2){
    STEP(jt+0, Sb0);
    STEP(jt+1, Sb1);
  }
  if constexpr (NSTEP == 40){
    STEP(36, Sb0);
    STEP(37, Sb1);
    STEP(38, Sb0);
    STEP(39, Sb1);
  }

  float gs[4], gq[4];
  #pragma unroll
  for (int mt=0;mt<4;mt++){ gs[mt]=0.f; gq[mt]=0.f; }
  #pragma unroll
  for (int mt=0;mt<4;mt++){
    #pragma unroll
    for (int r=0;r<4;r++){
      int co = co0 + mt*16 + quad*4 + r;
      float bb = bias[co] + (bias2 ? bias2[co] : 0.f) + (bias_bc ? bias_bc[b*NC + co] : 0.f);
      size_t ob = ((size_t)b*NC + co)*NHW + px0 + wave*32;
      #pragma unroll
      for (int nt=0;nt<2;nt++){
        size_t oi = ob + nt*16 + lm;
        float v = acc[mt][nt][r] + bb;
        if (addf) v += addf[oi];
        out[oi] = v;
        gs[mt] += v; gq[mt] += v*v;
      }
    }
  }
  #pragma unroll
  for (int mt=0;mt<4;mt++){
    float s = gs[mt], q = gq[mt];
    #pragma unroll
    for (int o=1;o<32;o<<=1){ s += __shfl_xor(s, o, 64); q += __shfl_xor(q, o, 64); }
    if ((lane&31) == 0){
      int g = (co0>>3) + mt*2 + (quad>>1);
      atomicAdd(&st[(b*32+g)*2+0], s);
      atomicAdd(&st[(b*32+g)*2+1], q);
    }
  }
}

// ---------------- MFMA GEMM qkv ----------------
__global__ __launch_bounds__(256)
void gemm_qkv_kernel(const short* __restrict__ ntp, const short* __restrict__ wqp,
                     short* __restrict__ qp, short* __restrict__ kp, short* __restrict__ vp){
  const int b = blockIdx.z;
  const int tid = threadIdx.x, wave = tid>>6, lane = tid&63;
  const int quad = lane>>4, lm = lane&15;
  const int M0 = blockIdx.y*128 + (wave>>1)*64;
  const int N0 = blockIdx.x*128 + (wave&1)*64;
  floatx4 acc[4][4];
  #pragma unroll
  for (int mt=0;mt<4;mt++)
    #pragma unroll
    for (int nt=0;nt<4;nt++) acc[mt][nt] = (floatx4){0.f,0.f,0.f,0.f};
  #pragma unroll
  for (int kk=0;kk<8;kk++){
    short8 af[4], bfr[4];
    #pragma unroll
    for (int mt=0;mt<4;mt++)
      af[mt] = *(const short8*)(wqp + ((size_t)kk*768 + M0 + mt*16 + lm)*32 + quad*8);
    #pragma unroll
    for (int nt=0;nt<4;nt++)
      bfr[nt] = *(const short8*)(ntp + (((size_t)b*8 + kk)*NHW + N0 + nt*16 + lm)*32 + quad*8);
    #pragma unroll
    for (int mt=0;mt<4;mt++)
      #pragma unroll
      for (int nt=0;nt<4;nt++)
        acc[mt][nt] = __builtin_amdgcn_mfma_f32_16x16x32_bf16(af[mt], bfr[nt], acc[mt][nt], 0,0,0);
  }
  #pragma unroll
  for (int mt=0;mt<4;mt++){
    int co_base = M0 + mt*16 + quad*4;
    int sec = co_base >> 8;
    int c = co_base & 255;
    #pragma unroll
    for (int nt=0;nt<4;nt++){
      int s = N0 + nt*16 + lm;
      if (sec < 2){
        unsigned short t0 = f2bu(acc[mt][nt][0]), t1 = f2bu(acc[mt][nt][1]);
        unsigned short t2 = f2bu(acc[mt][nt][2]), t3 = f2bu(acc[mt][nt][3]);
        uint2 w2; w2.x = ((unsigned)t1<<16)|t0; w2.y = ((unsigned)t3<<16)|t2;
        short* dst = (sec==0) ? qp : kp;
        *(uint2*)(dst + (((size_t)b*8 + (c>>5))*NHW + s)*32 + (c&31)) = w2;
      } else {
        #pragma unroll
        for (int r=0;r<4;r++)
          vp[(((size_t)b*32 + (s>>5))*NC + c + r)*32 + (s&31)] = (short)f2bu(acc[mt][nt][r]);
      }
    }
  }
}

// ---------------- MFMA fused attention: 64 q-rows/block, 16 waves, 256 blocks ----------------
__global__ __launch_bounds__(1024)
void attn_mfma_kernel(const short* __restrict__ qp, const short* __restrict__ kp,
                      const short* __restrict__ vp, short* __restrict__ op){
  const int bx = blockIdx.x;
  const int b = bx & 15;               // XCD pin: batches {b,b+8} -> XCD b&7 (32 blocks/XCD)
  const int s0 = (bx >> 4) * 64;
  const int tid = threadIdx.x, wave = tid>>6, lane = tid&63;
  const int quad = lane>>4, lm = lane&15;

  __shared__ short P[64*1024];         // 128 KB, XOR-swizzled granules
  __shared__ float red[64][16];        // reused for max then sum
  __shared__ float fred[64];           // reused for row-max then 1/row-sum

  // ---- phase 1: S = Q K^T ; wave covers rows[0..64) x cols[wave*64 .. +64) ----
  floatx4 sc[4][4];
  #pragma unroll
  for (int rt=0;rt<4;rt++)
    #pragma unroll
    for (int ti=0;ti<4;ti++) sc[rt][ti] = (floatx4){0.f,0.f,0.f,0.f};

  const int colb = wave*64;
  #pragma unroll
  for (int h=0;h<8;h++){
    const size_t hb = ((size_t)b*8 + h)*NHW;
    short8 aq[4], kf[4];
    #pragma unroll
    for (int rt=0;rt<4;rt++)
      aq[rt] = *(const short8*)(qp + (hb + s0 + rt*16 + lm)*32 + quad*8);
    #pragma unroll
    for (int ti=0;ti<4;ti++)
      kf[ti] = *(const short8*)(kp + (hb + colb + ti*16 + lm)*32 + quad*8);
    #pragma unroll
    for (int rt=0;rt<4;rt++)
      #pragma unroll
      for (int ti=0;ti<4;ti++)
        sc[rt][ti] = __builtin_amdgcn_mfma_f32_16x16x32_bf16(aq[rt], kf[ti], sc[rt][ti], 0,0,0);
  }

  // ---- softmax over rows (cols split across 16 waves) ----
  const float scale = 0.0625f;
  float mx[4][4];
  #pragma unroll
  for (int rt=0;rt<4;rt++)
    #pragma unroll
    for (int r=0;r<4;r++) mx[rt][r] = -1e30f;
  #pragma unroll
  for (int rt=0;rt<4;rt++)
    #pragma unroll
    for (int ti=0;ti<4;ti++)
      #pragma unroll
      for (int r=0;r<4;r++){
        float v = sc[rt][ti][r]*scale;
        sc[rt][ti][r] = v;
        mx[rt][r] = fmaxf(mx[rt][r], v);
      }
  #pragma unroll
  for (int o=1;o<16;o<<=1)
    #pragma unroll
    for (int rt=0;rt<4;rt++)
      #pragma unroll
      for (int r=0;r<4;r++) mx[rt][r] = fmaxf(mx[rt][r], __shfl_xor(mx[rt][r], o, 64));
  if (lm==0){
    #pragma unroll
    for (int rt=0;rt<4;rt++)
      #pragma unroll
      for (int r=0;r<4;r++) red[rt*16 + quad*4 + r][wave] = mx[rt][r];
  }
  __syncthreads();
  { // stage-2 max: 16 threads per row
    float v = red[tid>>4][tid&15];
    #pragma unroll
    for (int o=1;o<16;o<<=1) v = fmaxf(v, __shfl_xor(v, o, 64));
    if ((tid&15)==0) fred[tid>>4] = v;
  }
  __syncthreads();
  float fmr[4][4], sm[4][4];
  #pragma unroll
  for (int rt=0;rt<4;rt++)
    #pragma unroll
    for (int r=0;r<4;r++){ fmr[rt][r] = fred[rt*16 + quad*4 + r]; sm[rt][r] = 0.f; }
  #pragma unroll
  for (int rt=0;rt<4;rt++)
    #pragma unroll
    for (int ti=0;ti<4;ti++)
      #pragma unroll
      for (int r=0;r<4;r++){
        float e = __expf(sc[rt][ti][r] - fmr[rt][r]);
        sc[rt][ti][r] = e;
        sm[rt][r] += e;
      }
  #pragma unroll
  for (int o=1;o<16;o<<=1)
    #pragma unroll
    for (int rt=0;rt<4;rt++)
      #pragma unroll
      for (int r=0;r<4;r++) sm[rt][r] += __shfl_xor(sm[rt][r], o, 64);
  __syncthreads();   // red[] (max partials) dead -> safe to reuse for sums
  if (lm==0){
    #pragma unroll
    for (int rt=0;rt<4;rt++)
      #pragma unroll
      for (int r=0;r<4;r++) red[rt*16 + quad*4 + r][wave] = sm[rt][r];
  }
  __syncthreads();
  { // stage-2 sum -> 1/sum
    float v = red[tid>>4][tid&15];
    #pragma unroll
    for (int o=1;o<16;o<<=1) v += __shfl_xor(v, o, 64);
    if ((tid&15)==0) fred[tid>>4] = 1.f/v;
  }
  __syncthreads();
  float fir[4][4];
  #pragma unroll
  for (int rt=0;rt<4;rt++)
    #pragma unroll
    for (int r=0;r<4;r++) fir[rt][r] = fred[rt*16 + quad*4 + r];
  // write P normalized, swizzled: elem(row,col) at row*1024 + ((col>>3 ^ row&7)<<3) + (col&7)
  #pragma unroll
  for (int rt=0;rt<4;rt++)
    #pragma unroll
    for (int ti=0;ti<4;ti++)
      #pragma unroll
      for (int r=0;r<4;r++){
        int row = rt*16 + quad*4 + r;
        int col = colb + ti*16 + lm;
        int off = row*1024 + ((((col>>3) ^ (row&7))&127)<<3) + (col&7);
        P[off] = (short)f2bu(sc[rt][ti][r]*fir[rt][r]);
      }
  __syncthreads();

  // ---- phase 2: O = P V^T ; wave = (cg: 32 ch, sh: 32 s) ----
  const int cg = wave>>1, sh = wave&1;
  const int ch0 = cg*32;
  floatx4 oacc[2][2];
  #pragma unroll
  for (int mt=0;mt<2;mt++)
    #pragma unroll
    for (int nt=0;nt<2;nt++) oacc[mt][nt] = (floatx4){0.f,0.f,0.f,0.f};

  #pragma unroll
  for (int kk=0;kk<32;kk++){
    short8 pf[2], vf[2];
    #pragma unroll
    for (int mt=0;mt<2;mt++){
      int row = sh*32 + mt*16 + lm;
      int off = row*1024 + ((((kk*4 + quad) ^ (row&7))&127)<<3);
      pf[mt] = *(const short8*)(&P[off]);
    }
    #pragma unroll
    for (int nt=0;nt<2;nt++)
      vf[nt] = *(const short8*)(vp + (((size_t)b*32 + kk)*NC + ch0 + nt*16 + lm)*32 + quad*8);
    #pragma unroll
    for (int mt=0;mt<2;mt++)
      #pragma unroll
      for (int nt=0;nt<2;nt++)
        oacc[mt][nt] = __builtin_amdgcn_mfma_f32_16x16x32_bf16(pf[mt], vf[nt], oacc[mt][nt], 0,0,0);
  }

  // packed bf16 epilogue: o_p[b][cc][s][32]
  #pragma unroll
  for (int nt=0;nt<2;nt++){
    int c = ch0 + nt*16 + lm;
    int cc = c>>5, cl = c&31;
    #pragma unroll
    for (int mt=0;mt<2;mt++)
      #pragma unroll
      for (int r=0;r<4;r++){
        int s = s0 + sh*32 + mt*16 + quad*4 + r;
        op[(((size_t)b*8 + cc)*NHW + s)*32 + cl] = (short)f2bu(oacc[mt][nt][r]);
      }
  }
}

// ---------------- MFMA out-proj: out = W@o + out_b + h ----------------
__global__ __launch_bounds__(256)
void outproj_mfma_kernel(const short* __restrict__ op, const short* __restrict__ wop,
                         const float* __restrict__ obias, const float* __restrict__ h,
                         float* __restrict__ out){
  const int b = blockIdx.z;
  const int tid = threadIdx.x, wave = tid>>6, lane = tid&63;
  const int quad = lane>>4, lm = lane&15;
  const int M0 = blockIdx.y*128 + (wave>>1)*64;
  const int N0 = blockIdx.x*128 + (wave&1)*64;
  floatx4 acc[4][4];
  #pragma unroll
  for (int mt=0;mt<4;mt++)
    #pragma unroll
    for (int nt=0;nt<4;nt++) acc[mt][nt] = (floatx4){0.f,0.f,0.f,0.f};
  #pragma unroll
  for (int kk=0;kk<8;kk++){
    short8 af[4], bfr[4];
    #pragma unroll
    for (int mt=0;mt<4;mt++)
      af[mt] = *(const short8*)(wop + ((size_t)kk*256 + M0 + mt*16 + lm)*32 + quad*8);
    #pragma unroll
    for (int nt=0;nt<4;nt++)
      bfr[nt] = *(const short8*)(op + (((size_t)b*8 + kk)*NHW + N0 + nt*16 + lm)*32 + quad*8);
    #pragma unroll
    for (int mt=0;mt<4;mt++)
      #pragma unroll
      for (int nt=0;nt<4;nt++)
        acc[mt][nt] = __builtin_amdgcn_mfma_f32_16x16x32_bf16(af[mt], bfr[nt], acc[mt][nt], 0,0,0);
  }
  #pragma unroll
  for (int mt=0;mt<4;mt++){
    #pragma unroll
    for (int r=0;r<4;r++){
      int co = M0 + mt*16 + quad*4 + r;
      float bb = obias[co];
      size_t ob = ((size_t)b*NC + co)*NHW + N0;
      #pragma unroll
      for (int nt=0;nt<4;nt++){
        size_t oi = ob + nt*16 + lm;
        out[oi] = acc[mt][nt][r] + bb + h[oi];
      }
    }
  }
}

extern "C" void kernel_launch(void* const* d_in, const int* in_sizes, int n_in,
                              void* d_out, int out_size, void* d_ws, size_t ws_size,
                              hipStream_t stream){
  const float* x        = (const float*)d_in[0];
  const float* time_emb = (const float*)d_in[1];
  const float* c_in     = (const float*)d_in[2];
  const float* gn1_g    = (const float*)d_in[3];
  const float* gn1_b    = (const float*)d_in[4];
  const float* conv1_w  = (const float*)d_in[5];
  const float* conv1_b  = (const float*)d_in[6];
  const float* noise_w  = (const float*)d_in[7];
  const float* noise_b  = (const float*)d_in[8];
  const float* gn2_g    = (const float*)d_in[9];
  const float* gn2_b    = (const float*)d_in[10];
  const float* conv2_w  = (const float*)d_in[11];
  const float* conv2_b  = (const float*)d_in[12];
  const float* cfunc_w  = (const float*)d_in[13];
  const float* cfunc_b  = (const float*)d_in[14];
  const float* agn_g    = (const float*)d_in[15];
  const float* agn_b    = (const float*)d_in[16];
  const float* qkv_w    = (const float*)d_in[17];
  const float* out_w    = (const float*)d_in[18];
  const float* out_b    = (const float*)d_in[19];
  float* outp = (float*)d_out;

  // ---- workspace layout (~67 MB) ----
  float* ws = (float*)d_ws;
  float* buf_h = ws;                       // NP fp32
  float* buf_t = buf_h + NP;               // NP fp32 (early: cp bf16 alias; late: o_p bf16 alias)
  short* xpb   = (short*)(buf_t + NP);     // NP bf16
  short* qp    = xpb + NP;                 // NP bf16
  short* kp    = qp + NP;                  // NP bf16
  short* vp    = kp + NP;                  // NP bf16
  short* wp1   = vp + NP;                  // 589824
  short* wp2   = wp1 + 589824;             // 589824
  short* wqp   = wp2 + 589824;             // 196608
  short* wcp   = wqp + 196608;             // 65536
  short* wop   = wcp + 65536;              // 65536
  float* na    = (float*)(wop + 65536);    // NB*NC
  float* st    = na + NB*NC;               // 2048 floats (stats) + 2048 floats (zpad zeros)
  float* st2   = st;
  float* st3   = st + 1024;
  const short* zpadp = (const short*)(st + 2048);
  short* cp    = (short*)buf_t;            // alias (dead after conv2's fused cfunc)
  short* op    = (short*)buf_t;            // alias (written by attn after cp dead)

  // ---- fused prep: wprep3 + wprep1 + cvtc + noise + gn_t (5 launches -> 1) ----
  prep_mega_kernel<<<2832, 256, 0, stream>>>(
      conv1_w, conv2_w, wp1, wp2, st,
      qkv_w, cfunc_w, out_w, wqp, wcp, wop,
      c_in, cp,
      time_emb, noise_w, noise_b, na,
      x, gn1_g, gn1_b, xpb);
  // ---- ResnetBlock ----
  conv3_mfma_kernel<36><<<dim3(8, 4, NB), 256, 0, stream>>>(
      xpb, wp1, conv1_b, na, nullptr, buf_h, st2, zpadp, nullptr, nullptr, nullptr);
  gn_post_kernel<true><<<NB*32, 256, 0, stream>>>(buf_h, st2, gn2_g, gn2_b, xpb);
  // conv2 with fused cfunc (steps 36..39) + x residual in epilogue
  conv3_mfma_kernel<40><<<dim3(8, 4, NB), 256, 0, stream>>>(
      xpb, wp2, conv2_b, nullptr, x, buf_h, st3, zpadp, cp, wcp, cfunc_b);
  // ---- Attention ----
  gn_post_kernel<false><<<NB*32, 256, 0, stream>>>(buf_h, st3, agn_g, agn_b, xpb);
  gemm_qkv_kernel<<<dim3(8,6,NB), 256, 0, stream>>>(xpb, wqp, qp, kp, vp);
  attn_mfma_kernel<<<256, 1024, 0, stream>>>(qp, kp, vp, op);
  outproj_mfma_kernel<<<dim3(8,2,NB), 256, 0, stream>>>(op, wop, out_b, buf_h, outp);
}

// Round 17
// 303.487 us; speedup vs baseline: 1.0464x; 1.0464x over previous
//
#include <hip/hip_runtime.h>
#include <hip/hip_bf16.h>
#include <math.h>

typedef __hip_bfloat16 bf16;
typedef short short8 __attribute__((ext_vector_type(8)));
typedef float floatx4 __attribute__((ext_vector_type(4)));

#define NB 16
#define NC 256
#define NHW 1024
#define NNE 256
#define NP (NB*NC*NHW)

__device__ __forceinline__ unsigned short f2bu(float f){
  bf16 h = (bf16)f; return *(unsigned short*)&h;
}

// async 16B global -> LDS DMA (no VGPR round-trip; per-lane global src, linear LDS dest)
__device__ __forceinline__ void gload_lds16(const short* g, short* l){
  __builtin_amdgcn_global_load_lds(
      (const __attribute__((address_space(1))) void*)g,
      (__attribute__((address_space(3))) void*)l, 16, 0, 0);
}

// ---------------- MEGA-PREP: wprep3 + wprep1 + cvtc + noise + gn_t in ONE launch ------------
__global__ __launch_bounds__(256)
void prep_mega_kernel(const float* __restrict__ w1, const float* __restrict__ w2,
                      short* __restrict__ wp1, short* __restrict__ wp2,
                      float* __restrict__ st,
                      const float* __restrict__ wq, const float* __restrict__ wc,
                      const float* __restrict__ wo,
                      short* __restrict__ wqp, short* __restrict__ wcp,
                      short* __restrict__ wop,
                      const float* __restrict__ c_in, short* __restrict__ cp,
                      const float* __restrict__ emb, const float* __restrict__ nw,
                      const float* __restrict__ nb, float* __restrict__ na,
                      const float* __restrict__ x, const float* __restrict__ gn1_g,
                      const float* __restrict__ gn1_b, short* __restrict__ xp){
  __shared__ float smem[8224];            // 32.9 KB arena (cvtc needs 32*257)
  const int blk = blockIdx.x, tid = threadIdx.x;

  if (blk < 512){                         // ---- wprep3 ----
    int co = blk & 255;
    const float* w = (blk < 256) ? w1 : w2;
    short* wp = (blk < 256) ? wp1 : wp2;
    if (blk == 0){
      for (int i=tid;i<4096;i+=256) st[i] = 0.f;   // stats (2048) + zpad (2048 floats)
    }
    float* tmp = smem;                    // 2304 floats
    for (int i=tid;i<2304;i+=256) tmp[i] = w[(size_t)co*2304 + i];
    __syncthreads();
    for (int j=tid;j<2304;j+=256){
      int tap = j>>8, ci = j&255;
      wp[(((size_t)tap*8 + (ci>>5))*NC + co)*32 + (ci&31)] = (short)f2bu(tmp[ci*9 + tap]);
    }
  } else if (blk < 1792){                 // ---- wprep1 ----
    int bq = blk - 512;
    if (bq < 768){
      float v = wq[(size_t)bq*256 + tid];
      wqp[(((size_t)(tid>>5))*768 + bq)*32 + (tid&31)] = (short)f2bu(v);
    } else if (bq < 1024){
      int co = bq - 768;
      float v = wc[(size_t)co*256 + tid];
      wcp[(((size_t)(tid>>5))*256 + co)*32 + (tid&31)] = (short)f2bu(v);
    } else {
      int co = bq - 1024;
      float v = wo[(size_t)co*256 + tid];
      wop[(((size_t)(tid>>5))*256 + co)*32 + (tid&31)] = (short)f2bu(v);
    }
  } else if (blk < 2304){                 // ---- cvtc ----
    int j = blk - 1792;
    int pxc = j&3, cc = (j>>2)&7, b = j>>5;
    float* ld = smem;                     // [32][257]
    size_t gbase = ((size_t)b*NC + cc*32)*NHW + pxc*256;
    for (int r=0;r<32;r++) ld[r*257 + tid] = c_in[gbase + (size_t)r*NHW + tid];
    __syncthreads();
    short* dst = cp + (((size_t)b*8 + cc)*NHW + pxc*256)*32;
    for (int it=0;it<4;it++){
      int pxl = it*64 + (tid>>2), ckl = tid&3;
      short8 pk;
      #pragma unroll
      for (int e=0;e<8;e++) pk[e] = (short)f2bu(ld[(ckl*8+e)*257 + pxl]);
      *(short8*)(dst + (size_t)pxl*32 + ckl*8) = pk;
    }
  } else if (blk < 2320){                 // ---- noise ----
    int b = blk - 2304, c = tid;
    float* e = smem;
    e[c] = emb[b*NNE + c];
    __syncthreads();
    float acc = nb[c];
    for (int k=0;k<NNE;k++) acc += e[k]*nw[c*NNE+k];
    na[b*NC + c] = acc;
  } else {                                // ---- gn_t (gn1 + swish -> xp) ----
    int j = blk - 2320;
    int b = j >> 5, g = j & 31;
    const int GSZ = 8*NHW;
    size_t base = ((size_t)b*NC + g*8)*NHW;
    float s = 0.f, ss = 0.f;
    for (int i = tid; i < GSZ; i += 256){
      float v = x[base+i];
      s += v; ss += v*v;
    }
    float* rs = smem; float* rq = smem + 256;
    rs[tid] = s; rq[tid] = ss;
    __syncthreads();
    for (int off=128; off>0; off>>=1){
      if (tid < off){ rs[tid]+=rs[tid+off]; rq[tid]+=rq[tid+off]; }
      __syncthreads();
    }
    float mean = rs[0] * (1.f/GSZ);
    float var  = rq[0] * (1.f/GSZ) - mean*mean;
    float inv  = rsqrtf(var + 1e-5f);
    float gm[8], bt[8];
    #pragma unroll
    for (int jj=0;jj<8;jj++){ gm[jj] = gn1_g[g*8+jj]*inv; bt[jj] = gn1_b[g*8+jj]; }
    short* dst = xp + (((size_t)b*8 + (g>>2))*NHW)*32 + (g&3)*8;
    for (int px = tid; px < NHW; px += 256){
      short8 pk;
      #pragma unroll
      for (int jj=0;jj<8;jj++){
        float v = (x[base + jj*NHW + px] - mean)*gm[jj] + bt[jj];
        v = v / (1.f + __expf(-v));
        pk[jj] = (short)f2bu(v);
      }
      *(short8*)(dst + (size_t)px*32) = pk;
    }
  }
}

// ---------------- GroupNorm single-pass from precomputed stats ----------------
template<bool SWISH>
__global__ void gn_post_kernel(const float* __restrict__ src, const float* __restrict__ st,
                               const float* __restrict__ gamma, const float* __restrict__ beta,
                               short* __restrict__ xp){
  int b = blockIdx.x >> 5, g = blockIdx.x & 31;
  size_t base = ((size_t)b*NC + g*8)*NHW;
  int tid = threadIdx.x;
  float s  = st[(b*32+g)*2+0];
  float ss = st[(b*32+g)*2+1];
  float mean = s * (1.f/8192.f);
  float var  = ss * (1.f/8192.f) - mean*mean;
  float inv  = rsqrtf(var + 1e-5f);
  float gm[8], bt[8];
  #pragma unroll
  for (int j=0;j<8;j++){ gm[j] = gamma[g*8+j]*inv; bt[j] = beta[g*8+j]; }
  short* dst = xp + (((size_t)b*8 + (g>>2))*NHW)*32 + (g&3)*8;
  for (int px = tid; px < NHW; px += 256){
    short8 pk;
    #pragma unroll
    for (int j=0;j<8;j++){
      float v = (src[base + j*NHW + px] - mean)*gm[j] + bt[j];
      if (SWISH) v = v / (1.f + __expf(-v));
      pk[j] = (short)f2bu(v);
    }
    *(short8*)(dst + (size_t)px*32) = pk;
  }
}

// ---------------- MFMA conv3x3 (+ optional fused 1x1 cfunc as steps 36..39) -----------------
// Depth-2 counted-vmcnt pipeline + T2 swizzle (r16, verified). NSTEP=40 fuses cfunc.
template<int NSTEP>
__global__ __launch_bounds__(256,3)
void conv3_mfma_kernel(const short* __restrict__ xp, const short* __restrict__ wp,
                       const float* __restrict__ bias, const float* __restrict__ bias_bc,
                       const float* __restrict__ addf, float* __restrict__ out,
                       float* __restrict__ st, const short* __restrict__ zpad,
                       const short* __restrict__ cp2, const short* __restrict__ wcp2,
                       const float* __restrict__ bias2){
  const int b = blockIdx.z, bx = blockIdx.x, by = blockIdx.y;
  const int tid = threadIdx.x, wave = tid>>6, lane = tid&63;
  const int quad = lane>>4, lm = lane&15;
  const int co0 = by*64;
  const int px0 = bx*128, yb = bx*4;

  __shared__ short Sb0[12288], Sb1[12288]; // each: [0,4096)=A 64x64, [4096,12288)=B 128x64

  const int rowt = tid>>3;
  const int g2   = (tid&7) ^ ((tid>>3)&7); // logical granule feeding this linear slot
  const int kq2  = g2 & 3;
  const int ccs2 = g2 >> 2;
  const size_t b8 = (size_t)b*8*NHW*32;

  auto STAGE = [&](int j, short* S){
    if constexpr (NSTEP > 36){
      if (j >= 36){                        // ---- cfunc 1x1 step: cc = j-36 ----
        const int cc = j - 36;
        const short* wsrc = wcp2 + (size_t)(cc*2 + ccs2)*8192 + (co0 + rowt)*32 + kq2*8;
        #pragma unroll
        for (int i=0;i<2;i++)
          gload_lds16(wsrc + i*(32*32), S + tid*8 + i*2048);
        const short* xstep = cp2 + b8 + (size_t)(cc*2 + ccs2)*(NHW*32);
        #pragma unroll
        for (int i=0;i<4;i++)
          gload_lds16(xstep + ((yb+i)*32 + rowt)*32 + kq2*8, S + 4096 + tid*8 + i*2048);
        return;
      }
    }
    const int tap = j>>2, ccp = j&3;
    const int dyp = (tap*11)>>5;           // 0,0,0,1,1,1,2,2,2
    const int dx  = tap - dyp*3 - 1;
    const int dy  = dyp - 1;
    const short* wsrc = wp + (size_t)(tap*8 + ccp*2 + ccs2)*8192 + (co0 + rowt)*32 + kq2*8;
    #pragma unroll
    for (int i=0;i<2;i++)
      gload_lds16(wsrc + i*(32*32), S + tid*8 + i*2048);
    const short* xstep = xp + b8 + (size_t)(ccp*2 + ccs2)*(NHW*32);
    const int xx = rowt + dx;
    const bool xok = (unsigned)xx < 32u;
    #pragma unroll
    for (int i=0;i<4;i++){
      const int y = yb + i + dy;
      const short* src = (xok && (unsigned)y < 32u)
                       ? (xstep + (y*32 + xx)*32 + kq2*8)
                       : (zpad + kq2*8);
      gload_lds16(src, S + 4096 + tid*8 + i*2048);
    }
  };

  floatx4 acc[4][2];
  #pragma unroll
  for (int mt=0;mt<4;mt++)
    #pragma unroll
    for (int nt=0;nt<2;nt++) acc[mt][nt] = (floatx4){0.f,0.f,0.f,0.f};

  const int sl = lm & 7;                   // read-side swizzle key
  auto STEP = [&](int j, short* S){
    asm volatile("s_waitcnt vmcnt(6)" ::: "memory");
    __builtin_amdgcn_s_barrier();
    __builtin_amdgcn_sched_barrier(0);
    short8 Af[2][4], Bf[2][2];
    #pragma unroll
    for (int ka=0;ka<2;ka++){
      const int slot = ((ka*4 + quad) ^ sl) << 3;
      #pragma unroll
      for (int mt=0;mt<4;mt++)
        Af[ka][mt] = *(const short8*)(S + (mt*16+lm)*64 + slot);
      #pragma unroll
      for (int nt=0;nt<2;nt++)
        Bf[ka][nt] = *(const short8*)(S + 4096 + (wave*32 + nt*16 + lm)*64 + slot);
    }
    asm volatile("s_waitcnt lgkmcnt(0)" ::: "memory");
    __builtin_amdgcn_sched_barrier(0);     // rule #18
    __builtin_amdgcn_s_barrier();
    int jn = j + 2; if (jn > NSTEP-1) jn = NSTEP-1;
    STAGE(jn, S);
    __builtin_amdgcn_s_setprio(1);
    #pragma unroll
    for (int ka=0;ka<2;ka++)
      #pragma unroll
      for (int mt=0;mt<4;mt++)
        #pragma unroll
        for (int nt=0;nt<2;nt++)
          acc[mt][nt] = __builtin_amdgcn_mfma_f32_16x16x32_bf16(Af[ka][mt], Bf[ka][nt], acc[mt][nt], 0,0,0);
    __builtin_amdgcn_s_setprio(0);
  };

  STAGE(0, Sb0); STAGE(1, Sb1);            // 12 DMAs in flight per wave
  for (int jt=0; jt<36; jt+=2){
    STEP(jt+0, Sb0);
    STEP(jt+1, Sb1);
  }
  if constexpr (NSTEP == 40){
    STEP(36, Sb0);
    STEP(37, Sb1);
    STEP(38, Sb0);
    STEP(39, Sb1);
  }

  float gs[4], gq[4];
  #pragma unroll
  for (int mt=0;mt<4;mt++){ gs[mt]=0.f; gq[mt]=0.f; }
  #pragma unroll
  for (int mt=0;mt<4;mt++){
    #pragma unroll
    for (int r=0;r<4;r++){
      int co = co0 + mt*16 + quad*4 + r;
      float bb = bias[co] + (bias2 ? bias2[co] : 0.f) + (bias_bc ? bias_bc[b*NC + co] : 0.f);
      size_t ob = ((size_t)b*NC + co)*NHW + px0 + wave*32;
      #pragma unroll
      for (int nt=0;nt<2;nt++){
        size_t oi = ob + nt*16 + lm;
        float v = acc[mt][nt][r] + bb;
        if (addf) v += addf[oi];
        out[oi] = v;
        gs[mt] += v; gq[mt] += v*v;
      }
    }
  }
  #pragma unroll
  for (int mt=0;mt<4;mt++){
    float s = gs[mt], q = gq[mt];
    #pragma unroll
    for (int o=1;o<32;o<<=1){ s += __shfl_xor(s, o, 64); q += __shfl_xor(q, o, 64); }
    if ((lane&31) == 0){
      int g = (co0>>3) + mt*2 + (quad>>1);
      atomicAdd(&st[(b*32+g)*2+0], s);
      atomicAdd(&st[(b*32+g)*2+1], q);
    }
  }
}

// ---------------- MFMA GEMM qkv ----------------
__global__ __launch_bounds__(256)
void gemm_qkv_kernel(const short* __restrict__ ntp, const short* __restrict__ wqp,
                     short* __restrict__ qp, short* __restrict__ kp, short* __restrict__ vp){
  const int b = blockIdx.z;
  const int tid = threadIdx.x, wave = tid>>6, lane = tid&63;
  const int quad = lane>>4, lm = lane&15;
  const int M0 = blockIdx.y*128 + (wave>>1)*64;
  const int N0 = blockIdx.x*128 + (wave&1)*64;
  floatx4 acc[4][4];
  #pragma unroll
  for (int mt=0;mt<4;mt++)
    #pragma unroll
    for (int nt=0;nt<4;nt++) acc[mt][nt] = (floatx4){0.f,0.f,0.f,0.f};
  #pragma unroll
  for (int kk=0;kk<8;kk++){
    short8 af[4], bfr[4];
    #pragma unroll
    for (int mt=0;mt<4;mt++)
      af[mt] = *(const short8*)(wqp + ((size_t)kk*768 + M0 + mt*16 + lm)*32 + quad*8);
    #pragma unroll
    for (int nt=0;nt<4;nt++)
      bfr[nt] = *(const short8*)(ntp + (((size_t)b*8 + kk)*NHW + N0 + nt*16 + lm)*32 + quad*8);
    #pragma unroll
    for (int mt=0;mt<4;mt++)
      #pragma unroll
      for (int nt=0;nt<4;nt++)
        acc[mt][nt] = __builtin_amdgcn_mfma_f32_16x16x32_bf16(af[mt], bfr[nt], acc[mt][nt], 0,0,0);
  }
  #pragma unroll
  for (int mt=0;mt<4;mt++){
    int co_base = M0 + mt*16 + quad*4;
    int sec = co_base >> 8;
    int c = co_base & 255;
    #pragma unroll
    for (int nt=0;nt<4;nt++){
      int s = N0 + nt*16 + lm;
      if (sec < 2){
        unsigned short t0 = f2bu(acc[mt][nt][0]), t1 = f2bu(acc[mt][nt][1]);
        unsigned short t2 = f2bu(acc[mt][nt][2]), t3 = f2bu(acc[mt][nt][3]);
        uint2 w2; w2.x = ((unsigned)t1<<16)|t0; w2.y = ((unsigned)t3<<16)|t2;
        short* dst = (sec==0) ? qp : kp;
        *(uint2*)(dst + (((size_t)b*8 + (c>>5))*NHW + s)*32 + (c&31)) = w2;
      } else {
        #pragma unroll
        for (int r=0;r<4;r++)
          vp[(((size_t)b*32 + (s>>5))*NC + c + r)*32 + (s&31)] = (short)f2bu(acc[mt][nt][r]);
      }
    }
  }
}

// ---------------- MFMA fused attention + OUT-PROJ: 64 q-rows/block, 16 waves, 256 blocks ----
// After phase 2, O stays in LDS (reusing P, padded stride 40 shorts -> 2 lanes/bank, free);
// then the out-projection GEMM (M=256co x N=64s x K=256, A=wop from L2) + out_b + h residual
// runs in-block -> eliminates the outproj dispatch and the 16MB op round-trip.
__global__ __launch_bounds__(1024)
void attn_mfma_kernel(const short* __restrict__ qp, const short* __restrict__ kp,
                      const short* __restrict__ vp, const short* __restrict__ wopp,
                      const float* __restrict__ obias, const float* __restrict__ h,
                      float* __restrict__ out){
  const int bx = blockIdx.x;
  const int b = bx & 15;               // XCD pin: batches {b,b+8} -> XCD b&7 (32 blocks/XCD)
  const int s0 = (bx >> 4) * 64;
  const int tid = threadIdx.x, wave = tid>>6, lane = tid&63;
  const int quad = lane>>4, lm = lane&15;

  __shared__ short P[64*1024];         // 128 KB; P matrix, then reused as OL (O tile, stride 40)
  __shared__ float red[64][16];        // reused for max then sum
  __shared__ float fred[64];           // reused for row-max then 1/row-sum

  // ---- phase 1: S = Q K^T ; wave covers rows[0..64) x cols[wave*64 .. +64) ----
  floatx4 sc[4][4];
  #pragma unroll
  for (int rt=0;rt<4;rt++)
    #pragma unroll
    for (int ti=0;ti<4;ti++) sc[rt][ti] = (floatx4){0.f,0.f,0.f,0.f};

  const int colb = wave*64;
  #pragma unroll
  for (int h8=0;h8<8;h8++){
    const size_t hb = ((size_t)b*8 + h8)*NHW;
    short8 aq[4], kf[4];
    #pragma unroll
    for (int rt=0;rt<4;rt++)
      aq[rt] = *(const short8*)(qp + (hb + s0 + rt*16 + lm)*32 + quad*8);
    #pragma unroll
    for (int ti=0;ti<4;ti++)
      kf[ti] = *(const short8*)(kp + (hb + colb + ti*16 + lm)*32 + quad*8);
    #pragma unroll
    for (int rt=0;rt<4;rt++)
      #pragma unroll
      for (int ti=0;ti<4;ti++)
        sc[rt][ti] = __builtin_amdgcn_mfma_f32_16x16x32_bf16(aq[rt], kf[ti], sc[rt][ti], 0,0,0);
  }

  // ---- softmax over rows (cols split across 16 waves) ----
  const float scale = 0.0625f;
  float mx[4][4];
  #pragma unroll
  for (int rt=0;rt<4;rt++)
    #pragma unroll
    for (int r=0;r<4;r++) mx[rt][r] = -1e30f;
  #pragma unroll
  for (int rt=0;rt<4;rt++)
    #pragma unroll
    for (int ti=0;ti<4;ti++)
      #pragma unroll
      for (int r=0;r<4;r++){
        float v = sc[rt][ti][r]*scale;
        sc[rt][ti][r] = v;
        mx[rt][r] = fmaxf(mx[rt][r], v);
      }
  #pragma unroll
  for (int o=1;o<16;o<<=1)
    #pragma unroll
    for (int rt=0;rt<4;rt++)
      #pragma unroll
      for (int r=0;r<4;r++) mx[rt][r] = fmaxf(mx[rt][r], __shfl_xor(mx[rt][r], o, 64));
  if (lm==0){
    #pragma unroll
    for (int rt=0;rt<4;rt++)
      #pragma unroll
      for (int r=0;r<4;r++) red[rt*16 + quad*4 + r][wave] = mx[rt][r];
  }
  __syncthreads();
  { // stage-2 max: 16 threads per row
    float v = red[tid>>4][tid&15];
    #pragma unroll
    for (int o=1;o<16;o<<=1) v = fmaxf(v, __shfl_xor(v, o, 64));
    if ((tid&15)==0) fred[tid>>4] = v;
  }
  __syncthreads();
  float fmr[4][4], sm[4][4];
  #pragma unroll
  for (int rt=0;rt<4;rt++)
    #pragma unroll
    for (int r=0;r<4;r++){ fmr[rt][r] = fred[rt*16 + quad*4 + r]; sm[rt][r] = 0.f; }
  #pragma unroll
  for (int rt=0;rt<4;rt++)
    #pragma unroll
    for (int ti=0;ti<4;ti++)
      #pragma unroll
      for (int r=0;r<4;r++){
        float e = __expf(sc[rt][ti][r] - fmr[rt][r]);
        sc[rt][ti][r] = e;
        sm[rt][r] += e;
      }
  #pragma unroll
  for (int o=1;o<16;o<<=1)
    #pragma unroll
    for (int rt=0;rt<4;rt++)
      #pragma unroll
      for (int r=0;r<4;r++) sm[rt][r] += __shfl_xor(sm[rt][r], o, 64);
  __syncthreads();   // red[] (max partials) dead -> safe to reuse for sums
  if (lm==0){
    #pragma unroll
    for (int rt=0;rt<4;rt++)
      #pragma unroll
      for (int r=0;r<4;r++) red[rt*16 + quad*4 + r][wave] = sm[rt][r];
  }
  __syncthreads();
  { // stage-2 sum -> 1/sum
    float v = red[tid>>4][tid&15];
    #pragma unroll
    for (int o=1;o<16;o<<=1) v += __shfl_xor(v, o, 64);
    if ((tid&15)==0) fred[tid>>4] = 1.f/v;
  }
  __syncthreads();
  float fir[4][4];
  #pragma unroll
  for (int rt=0;rt<4;rt++)
    #pragma unroll
    for (int r=0;r<4;r++) fir[rt][r] = fred[rt*16 + quad*4 + r];
  // write P normalized, swizzled: elem(row,col) at row*1024 + ((col>>3 ^ row&7)<<3) + (col&7)
  #pragma unroll
  for (int rt=0;rt<4;rt++)
    #pragma unroll
    for (int ti=0;ti<4;ti++)
      #pragma unroll
      for (int r=0;r<4;r++){
        int row = rt*16 + quad*4 + r;
        int col = colb + ti*16 + lm;
        int off = row*1024 + ((((col>>3) ^ (row&7))&127)<<3) + (col&7);
        P[off] = (short)f2bu(sc[rt][ti][r]*fir[rt][r]);
      }
  __syncthreads();

  // ---- phase 2: O = P V^T ; wave = (cg: 32 ch, sh: 32 s) ----
  const int cg = wave>>1, sh = wave&1;
  const int ch0 = cg*32;
  floatx4 oacc[2][2];
  #pragma unroll
  for (int mt=0;mt<2;mt++)
    #pragma unroll
    for (int nt=0;nt<2;nt++) oacc[mt][nt] = (floatx4){0.f,0.f,0.f,0.f};

  #pragma unroll
  for (int kk=0;kk<32;kk++){
    short8 pf[2], vf[2];
    #pragma unroll
    for (int mt=0;mt<2;mt++){
      int row = sh*32 + mt*16 + lm;
      int off = row*1024 + ((((kk*4 + quad) ^ (row&7))&127)<<3);
      pf[mt] = *(const short8*)(&P[off]);
    }
    #pragma unroll
    for (int nt=0;nt<2;nt++)
      vf[nt] = *(const short8*)(vp + (((size_t)b*32 + kk)*NC + ch0 + nt*16 + lm)*32 + quad*8);
    #pragma unroll
    for (int mt=0;mt<2;mt++)
      #pragma unroll
      for (int nt=0;nt<2;nt++)
        oacc[mt][nt] = __builtin_amdgcn_mfma_f32_16x16x32_bf16(pf[mt], vf[nt], oacc[mt][nt], 0,0,0);
  }

  // ---- O -> LDS (OL): OL[cc][s_local][cl], row stride 40 shorts (pad -> 2 lanes/bank) ----
  __syncthreads();   // all P reads complete before overwriting P's low rows with OL
  #pragma unroll
  for (int nt=0;nt<2;nt++){
    int cl = nt*16 + lm;
    #pragma unroll
    for (int mt=0;mt<2;mt++)
      #pragma unroll
      for (int r=0;r<4;r++){
        int sl2 = sh*32 + mt*16 + quad*4 + r;
        P[(cg*64 + sl2)*40 + cl] = (short)f2bu(oacc[mt][nt][r]);
      }
  }
  __syncthreads();

  // ---- fused out-proj: out[co][s] = sum_c wop[co][c]*O[c][s] + out_b[co] + h[co][s] ----
  const int cog = wave>>2, sg = wave&3;     // 4 co-groups x 4 s-groups
  const int co0w = cog*64, sl0 = sg*16;
  floatx4 pacc[4];
  #pragma unroll
  for (int mt=0;mt<4;mt++) pacc[mt] = (floatx4){0.f,0.f,0.f,0.f};
  #pragma unroll
  for (int kk=0;kk<8;kk++){
    short8 af[4];
    #pragma unroll
    for (int mt=0;mt<4;mt++)
      af[mt] = *(const short8*)(wopp + ((size_t)kk*256 + co0w + mt*16 + lm)*32 + quad*8);
    short8 bfr = *(const short8*)(&P[(kk*64 + sl0 + lm)*40 + quad*8]);
    #pragma unroll
    for (int mt=0;mt<4;mt++)
      pacc[mt] = __builtin_amdgcn_mfma_f32_16x16x32_bf16(af[mt], bfr, pacc[mt], 0,0,0);
  }
  #pragma unroll
  for (int mt=0;mt<4;mt++){
    #pragma unroll
    for (int r=0;r<4;r++){
      int co = co0w + mt*16 + quad*4 + r;
      float bb = obias[co];
      size_t oi = ((size_t)b*NC + co)*NHW + s0 + sl0 + lm;
      out[oi] = pacc[mt][r] + bb + h[oi];
    }
  }
}

extern "C" void kernel_launch(void* const* d_in, const int* in_sizes, int n_in,
                              void* d_out, int out_size, void* d_ws, size_t ws_size,
                              hipStream_t stream){
  const float* x        = (const float*)d_in[0];
  const float* time_emb = (const float*)d_in[1];
  const float* c_in     = (const float*)d_in[2];
  const float* gn1_g    = (const float*)d_in[3];
  const float* gn1_b    = (const float*)d_in[4];
  const float* conv1_w  = (const float*)d_in[5];
  const float* conv1_b  = (const float*)d_in[6];
  const float* noise_w  = (const float*)d_in[7];
  const float* noise_b  = (const float*)d_in[8];
  const float* gn2_g    = (const float*)d_in[9];
  const float* gn2_b    = (const float*)d_in[10];
  const float* conv2_w  = (const float*)d_in[11];
  const float* conv2_b  = (const float*)d_in[12];
  const float* cfunc_w  = (const float*)d_in[13];
  const float* cfunc_b  = (const float*)d_in[14];
  const float* agn_g    = (const float*)d_in[15];
  const float* agn_b    = (const float*)d_in[16];
  const float* qkv_w    = (const float*)d_in[17];
  const float* out_w    = (const float*)d_in[18];
  const float* out_b    = (const float*)d_in[19];
  float* outp = (float*)d_out;

  // ---- workspace layout (~67 MB) ----
  float* ws = (float*)d_ws;
  float* buf_h = ws;                       // NP fp32
  float* buf_t = buf_h + NP;               // NP fp32 (cp bf16 alias)
  short* xpb   = (short*)(buf_t + NP);     // NP bf16
  short* qp    = xpb + NP;                 // NP bf16
  short* kp    = qp + NP;                  // NP bf16
  short* vp    = kp + NP;                  // NP bf16
  short* wp1   = vp + NP;                  // 589824
  short* wp2   = wp1 + 589824;             // 589824
  short* wqp   = wp2 + 589824;             // 196608
  short* wcp   = wqp + 196608;             // 65536
  short* wop   = wcp + 65536;              // 65536
  float* na    = (float*)(wop + 65536);    // NB*NC
  float* st    = na + NB*NC;               // 2048 floats (stats) + 2048 floats (zpad zeros)
  float* st2   = st;
  float* st3   = st + 1024;
  const short* zpadp = (const short*)(st + 2048);
  short* cp    = (short*)buf_t;            // alias (dead after conv2's fused cfunc)

  // ---- fused prep: wprep3 + wprep1 + cvtc + noise + gn_t (5 launches -> 1) ----
  prep_mega_kernel<<<2832, 256, 0, stream>>>(
      conv1_w, conv2_w, wp1, wp2, st,
      qkv_w, cfunc_w, out_w, wqp, wcp, wop,
      c_in, cp,
      time_emb, noise_w, noise_b, na,
      x, gn1_g, gn1_b, xpb);
  // ---- ResnetBlock ----
  conv3_mfma_kernel<36><<<dim3(8, 4, NB), 256, 0, stream>>>(
      xpb, wp1, conv1_b, na, nullptr, buf_h, st2, zpadp, nullptr, nullptr, nullptr);
  gn_post_kernel<true><<<NB*32, 256, 0, stream>>>(buf_h, st2, gn2_g, gn2_b, xpb);
  // conv2 with fused cfunc (steps 36..39) + x residual in epilogue
  conv3_mfma_kernel<40><<<dim3(8, 4, NB), 256, 0, stream>>>(
      xpb, wp2, conv2_b, nullptr, x, buf_h, st3, zpadp, cp, wcp, cfunc_b);
  // ---- Attention (with fused out-projection) ----
  gn_post_kernel<false><<<NB*32, 256, 0, stream>>>(buf_h, st3, agn_g, agn_b, xpb);
  gemm_qkv_kernel<<<dim3(8,6,NB), 256, 0, stream>>>(xpb, wqp, qp, kp, vp);
  attn_mfma_kernel<<<256, 1024, 0, stream>>>(qp, kp, vp, wop, out_b, buf_h, outp);
}